// Round 19
// baseline (110.812 us; speedup 1.0000x reference)
//
#include <hip/hip_runtime.h>

// ActorGCN collapsed-linear, dst-bucketed tile pipeline v4, 8 dispatches.
// Identity: A(xW) = (Ax)W; BN stats of h = yW+b reduce to the 20x20
// covariance of y = A x. Hidden [N,1024] never materialized.
//
// Round 19: r18's k_tile = 50.5us, latency-bound (VALUBusy 13.6%, 10% HBM).
// Diagnosis: same random x-gather as r16's scatter (45us @ 65% occupancy),
// but the tile kernel has 10x fewer waves -> no TLP to hide L3 latency.
// Fix = MLP instead of TLP:
//  (a) edge loop unrolled x4 with phase separation: 4 independent x-gathers
//      issued BEFORE any LDS atomic (LDS atomics are ordered program points;
//      interleaving serializes the gathers).
//  (b) records packed to uint2 (src|dlow<<22, ns bits): one 8B load/item.
// Rest unchanged from r18 (counts-from-deg, padded cursors, payload-inline
// records, LDS-atomic tile, fused self-term + y write + stats).
//
// Workspace (floats): deg N | y 20N | stats 256 | params 64, then (ints)
// counts NB | bstart NB+1 | cursor NB*32 | erec8 2*E (uint2).

#define F 20
#define NSTAT 230
#define SROWS 256
#define BSZ 256
#define TBSZ 512
#define CPAD 32  // cursor padding stride (ints) = 128B line

__global__ void k_init(float* __restrict__ deg, float* __restrict__ stats, int N) {
  int i = blockIdx.x * blockDim.x + threadIdx.x;
  if (i < N) deg[i] = 0.f;  // self-loop added at use: deg_true = deg + 1
  if (i < 256) stats[i] = 0.f;
}

// plain degree histogram: atomics spread over 832KB -> no hot lines.
__global__ void k_deg_acc(const int* __restrict__ dst, float* __restrict__ deg, int E) {
  int e = blockIdx.x * blockDim.x + threadIdx.x;
  if (e < E) atomicAdd(&deg[dst[e]], 1.0f);
}

// counts[b] = sum of deg over rows [b*256, b*256+256) — no atomics.
__global__ __launch_bounds__(BSZ) void k_counts(const float* __restrict__ deg,
                                                int* __restrict__ counts, int N) {
  __shared__ float s[BSZ];
  int t = threadIdx.x;
  long row = (long)blockIdx.x * SROWS + t;
  s[t] = (row < N) ? deg[row] : 0.f;
  __syncthreads();
  for (int off = 128; off; off >>= 1) {
    if (t < off) s[t] += s[t + off];
    __syncthreads();
  }
  if (t == 0) counts[blockIdx.x] = (int)(s[0] + 0.5f);
}

// exclusive scan of NB (<=1024) bucket counts; writes bstart + padded cursor.
__global__ __launch_bounds__(1024) void k_scan(const int* __restrict__ counts,
                                               int* __restrict__ bstart,
                                               int* __restrict__ cursor,
                                               int NB, int E) {
  __shared__ int s[1024];
  int t = threadIdx.x;
  int c = (t < NB) ? counts[t] : 0;
  s[t] = c;
  __syncthreads();
  for (int off = 1; off < 1024; off <<= 1) {
    int v = (t >= off) ? s[t - off] : 0;
    __syncthreads();
    s[t] += v;
    __syncthreads();
  }
  if (t < NB) {
    int excl = s[t] - c;
    bstart[t] = excl;
    cursor[t * CPAD] = excl;  // one counter per 128B line
  }
  if (t == 0) bstart[NB] = E;
}

// bucket fill, payload inline, packed uint2 record.
__global__ void k_fill(const int* __restrict__ src, const int* __restrict__ dst,
                       const float* __restrict__ deg, int* __restrict__ cursor,
                       uint2* __restrict__ erec8, int E) {
  int e = blockIdx.x * blockDim.x + threadIdx.x;
  if (e >= E) return;
  int s = src[e];
  int d = dst[e];
  int pos = atomicAdd(&cursor[(d >> 8) * CPAD], 1);
  uint2 r;
  r.x = (unsigned int)s | ((unsigned int)(d & 255) << 22);
  r.y = __float_as_uint(rsqrtf(deg[s] + 1.0f));
  erec8[pos] = r;
}

// Block b owns dst rows [b*256, b*256+256). Edge loop unrolled x4:
// load phase (4 independent record loads + x-gathers) then atomic phase.
__global__ __launch_bounds__(TBSZ) void k_tile(
    const uint2* __restrict__ erec8, const int* __restrict__ bstart,
    const float* __restrict__ deg,
    const float* __restrict__ state, const float* __restrict__ edge_attr,
    float* __restrict__ y, float* __restrict__ stats, int N, int Ns) {
  __shared__ float tile[SROWS * F];  // 20 KB
  __shared__ float pp[2][NSTAT];     // partials
  int t = threadIdx.x;

  for (int i4 = t; i4 < SROWS * 5; i4 += TBSZ)
    *reinterpret_cast<float4*>(tile + i4 * 4) = make_float4(0.f, 0.f, 0.f, 0.f);
  __syncthreads();

  // ---- edge accumulation, 4-way MLP ----
  int start = bstart[blockIdx.x];
  int cnt = bstart[blockIdx.x + 1] - start;
  int sb = Ns * F;
  int nit = cnt * F;
  for (int it0 = t; it0 < nit; it0 += 4 * TBSZ) {
    float val[4];
    int ad[4];
    bool on[4];
    #pragma unroll
    for (int u = 0; u < 4; ++u) {
      int it = it0 + u * TBSZ;
      on[u] = (it < nit);
      val[u] = 0.f;
      ad[u] = 0;
      if (on[u]) {
        int le = it / F;
        int f = it - le * F;
        uint2 r = erec8[start + le];  // one 8B load, ~broadcast across lanes
        int s = r.x & 0x3FFFFF;
        int dlow = r.x >> 22;
        float ns = __uint_as_float(r.y);
        int xi = s * F + f;
        float x = (xi < sb) ? state[xi] : edge_attr[xi - sb];  // THE gather
        val[u] = ns * x;
        ad[u] = dlow * F + f;
      }
    }
    #pragma unroll
    for (int u = 0; u < 4; ++u)
      if (on[u]) atomicAdd(&tile[ad[u]], val[u]);
  }
  __syncthreads();

  // ---- self-term: y_full = dinv*(z + dinv*x); single streaming writeback ----
  long rowbase = (long)blockIdx.x * SROWS;
  for (int i4 = t; i4 < SROWS * 5; i4 += TBSZ) {
    int rl = i4 / 5;
    int q = i4 - rl * 5;
    long row = rowbase + rl;
    float4 v = make_float4(0.f, 0.f, 0.f, 0.f);
    if (row < N) {
      float4 zv = *reinterpret_cast<const float4*>(tile + i4 * 4);
      const float* xrow = (row < (long)Ns) ? (state + row * F)
                                           : (edge_attr + (row - Ns) * F);
      float4 xv = *reinterpret_cast<const float4*>(xrow + q * 4);
      float di = rsqrtf(deg[row] + 1.0f);
      v.x = di * (zv.x + di * xv.x);
      v.y = di * (zv.y + di * xv.y);
      v.z = di * (zv.z + di * xv.z);
      v.w = di * (zv.w + di * xv.w);
      *reinterpret_cast<float4*>(y + row * F + q * 4) = v;  // for k_out
    }
    *reinterpret_cast<float4*>(tile + i4 * 4) = v;
  }
  __syncthreads();

  // ---- stats from LDS tile: 2 row-groups x 128 rows in parallel ----
  int g = t >> 8;   // 0..1
  int c = t & 255;
  int r0 = g * 128;
  if (c < F) {
    float a0 = 0.f, a1 = 0.f, a2 = 0.f, a3 = 0.f;
    for (int r = r0; r < r0 + 128; r += 4) {
      a0 += tile[(r + 0) * F + c];
      a1 += tile[(r + 1) * F + c];
      a2 += tile[(r + 2) * F + c];
      a3 += tile[(r + 3) * F + c];
    }
    pp[g][c] = (a0 + a1) + (a2 + a3);
  } else if (c < NSTAT) {
    int k = c - F, i = 0;
    while (k >= F - i) { k -= F - i; i++; }
    int ci = i, cj = i + k;
    float a0 = 0.f, a1 = 0.f, a2 = 0.f, a3 = 0.f;
    for (int r = r0; r < r0 + 128; r += 4) {
      a0 += tile[(r + 0) * F + ci] * tile[(r + 0) * F + cj];
      a1 += tile[(r + 1) * F + ci] * tile[(r + 1) * F + cj];
      a2 += tile[(r + 2) * F + ci] * tile[(r + 2) * F + cj];
      a3 += tile[(r + 3) * F + ci] * tile[(r + 3) * F + cj];
    }
    pp[g][c] = (a0 + a1) + (a2 + a3);
  }
  __syncthreads();
  if (t < NSTAT) atomicAdd(&stats[t], pp[0][t] + pp[1][t]);
}

// Single block, 256 threads, launch_bounds(256,1): 4 waves -> up to 512
// VGPR/thread; w[4][20] + m0[20] + m1[20] live in registers (round-4 proven).
__global__ __launch_bounds__(256, 1) void k_finalize(
    const float* __restrict__ stats,
    const float* __restrict__ W_gcn,
    const float* __restrict__ gamma,
    const float* __restrict__ beta,
    const float* __restrict__ W_lin,
    const float* __restrict__ b_lin,
    float* __restrict__ params,
    int N, int H) {
  __shared__ float Cu_s[210];
  __shared__ float ybar_s[F];
  __shared__ float part[4][44];
  int t = threadIdx.x;
  int lane = t & 63;
  int wv = t >> 6;
  float invN = 1.0f / (float)N;
  if (t < F) ybar_s[t] = stats[t] * invN;
  __syncthreads();
  if (t < 210) {
    int k = t, i = 0;
    while (k >= F - i) { k -= F - i; i++; }
    int j = i + k;
    float cv = stats[F + t] * invN - ybar_s[i] * ybar_s[j];
    Cu_s[t] = (i == j) ? cv : 2.0f * cv;  // fold symmetry factor
  }
  __syncthreads();

  float m0[F], m1[F];
  #pragma unroll
  for (int f = 0; f < F; ++f) { m0[f] = 0.f; m1[f] = 0.f; }
  float d0 = 0.f, d1 = 0.f;

  for (int hb = 0; hb < H; hb += 4 * 256) {
    float w[4][F];
    float var[4];
    int hh[4];
    bool act[4];
    #pragma unroll
    for (int c = 0; c < 4; ++c) {
      int h = hb + c * 256 + t;
      act[c] = (h < H);
      hh[c] = act[c] ? h : 0;
      var[c] = 0.f;
      #pragma unroll
      for (int f = 0; f < F; ++f) {
        float x = W_gcn[f * H + hh[c]];  // coalesced over t
        w[c][f] = act[c] ? x : 0.f;
      }
    }
    int p = 0;
    #pragma unroll
    for (int i = 0; i < F; ++i) {
      #pragma unroll
      for (int j = i; j < F; ++j) {
        float cu = Cu_s[p];  // uniform broadcast, reused 4x
        ++p;
        #pragma unroll
        for (int c = 0; c < 4; ++c) var[c] += cu * (w[c][i] * w[c][j]);
      }
    }
    #pragma unroll
    for (int c = 0; c < 4; ++c) {
      float sg = act[c] ? (gamma[hh[c]] * rsqrtf(var[c] + 1e-5f)) : 0.f;
      float wl0 = W_lin[hh[c] * 2 + 0], wl1 = W_lin[hh[c] * 2 + 1];
      float s0 = sg * wl0, s1 = sg * wl1;
      #pragma unroll
      for (int f = 0; f < F; ++f) { m0[f] += w[c][f] * s0; m1[f] += w[c][f] * s1; }
      float bt = act[c] ? beta[hh[c]] : 0.f;
      d0 += bt * wl0;
      d1 += bt * wl1;
    }
  }

  #pragma unroll
  for (int f = 0; f < F; ++f) {
    float v0 = m0[f], v1 = m1[f];
    #pragma unroll
    for (int off = 32; off; off >>= 1) {
      v0 += __shfl_xor(v0, off);
      v1 += __shfl_xor(v1, off);
    }
    if (lane == 0) { part[wv][2 * f] = v0; part[wv][2 * f + 1] = v1; }
  }
  #pragma unroll
  for (int off = 32; off; off >>= 1) {
    d0 += __shfl_xor(d0, off);
    d1 += __shfl_xor(d1, off);
  }
  if (lane == 0) { part[wv][40] = d0; part[wv][41] = d1; }
  __syncthreads();

  if (t < 42) {
    float acc = 0.f;
    for (int w2 = 0; w2 < 4; ++w2) acc += part[w2][t];
    if (t >= 40) acc += b_lin[t - 40];
    params[t] = acc;
  } else if (t < 62) {
    params[t] = ybar_s[t - 42];
  }
}

// thread per node: logits = (y[n]-ybar) @ M + d; relu; 2-way softmax.
__global__ void k_out(const float* __restrict__ y,
                      const float* __restrict__ params,
                      float* __restrict__ out, int N) {
  __shared__ float P[64];
  if (threadIdx.x < 62) P[threadIdx.x] = params[threadIdx.x];
  __syncthreads();
  int n = blockIdx.x * blockDim.x + threadIdx.x;
  if (n >= N) return;
  const float4* yr4 = reinterpret_cast<const float4*>(y + (size_t)n * F);
  float l0 = P[40], l1 = P[41];
  #pragma unroll
  for (int k = 0; k < 5; ++k) {
    float4 q = yr4[k];
    float vv[4] = {q.x, q.y, q.z, q.w};
    #pragma unroll
    for (int u = 0; u < 4; ++u) {
      int f = 4 * k + u;
      float dv = vv[u] - P[42 + f];
      l0 += dv * P[2 * f + 0];
      l1 += dv * P[2 * f + 1];
    }
  }
  l0 = fmaxf(l0, 0.f);
  l1 = fmaxf(l1, 0.f);
  float m = fmaxf(l0, l1);
  float e0 = __expf(l0 - m), e1 = __expf(l1 - m);
  float inv = 1.0f / (e0 + e1);
  float2 o2;
  o2.x = e0 * inv;
  o2.y = e1 * inv;
  reinterpret_cast<float2*>(out)[n] = o2;
}

extern "C" void kernel_launch(void* const* d_in, const int* in_sizes, int n_in,
                              void* d_out, int out_size, void* d_ws, size_t ws_size,
                              hipStream_t stream) {
  const float* state     = (const float*)d_in[0];
  const float* edge_attr = (const float*)d_in[1];
  const int*   eidx      = (const int*)d_in[2];
  const float* W_gcn     = (const float*)d_in[3];
  // d_in[4] = b_gcn: cancels inside batchnorm, unused.
  const float* gamma     = (const float*)d_in[5];
  const float* beta      = (const float*)d_in[6];
  const float* W_lin     = (const float*)d_in[7];
  const float* b_lin     = (const float*)d_in[8];
  float* out = (float*)d_out;

  int Ns = in_sizes[0] / F;
  int E  = in_sizes[2] / 2;
  int N  = Ns + in_sizes[1] / F;
  int H  = in_sizes[4];

  const int* src = eidx;
  const int* dst = eidx + E;

  int NB = (N + SROWS - 1) / SROWS;  // 814 for N=208192 (<=1024 for k_scan)

  float* ws     = (float*)d_ws;
  float* deg    = ws;
  float* y      = ws + N;
  float* stats  = y + (size_t)N * F;
  float* params = stats + 256;
  int*   counts = (int*)(params + 64);
  int*   bstart = counts + NB;
  int*   cursor = bstart + NB + 1;           // NB*CPAD ints, padded
  uint2* erec8  = (uint2*)(cursor + NB * CPAD);

  k_init<<<(N + BSZ - 1) / BSZ, BSZ, 0, stream>>>(deg, stats, N);
  k_deg_acc<<<(E + BSZ - 1) / BSZ, BSZ, 0, stream>>>(dst, deg, E);
  k_counts<<<NB, BSZ, 0, stream>>>(deg, counts, N);
  k_scan<<<1, 1024, 0, stream>>>(counts, bstart, cursor, NB, E);
  k_fill<<<(E + BSZ - 1) / BSZ, BSZ, 0, stream>>>(src, dst, deg, cursor,
                                                  erec8, E);
  k_tile<<<NB, TBSZ, 0, stream>>>(erec8, bstart, deg, state, edge_attr,
                                  y, stats, N, Ns);
  k_finalize<<<1, 256, 0, stream>>>(stats, W_gcn, gamma, beta, W_lin, b_lin,
                                    params, N, H);
  k_out<<<(N + BSZ - 1) / BSZ, BSZ, 0, stream>>>(y, params, out, N);
}

// Round 20
// 94.915 us; speedup vs baseline: 1.1675x; 1.1675x over previous
//
#include <hip/hip_runtime.h>

// ActorGCN collapsed-linear, dst-bucketed tile pipeline v5, 8 dispatches.
// Identity: A(xW) = (Ax)W; BN stats of h = yW+b reduce to the 20x20
// covariance of y = A x. Hidden [N,1024] never materialized.
//
// Round 20: r19 MLP unroll = null (55us, VALUBusy 13%) -> not per-wave
// load-depth-limited. But k_tile occupancy is only 27% vs r16 scatter's 65%
// doing the same gather in 45us -> the tile kernel is TLP-starved, not
// path-saturated. Fix: SROWS 256->128, TBSZ 512->256 -> 1627 blocks
// (6.4/CU, ~25 waves/CU; LDS 12KB), simple r18 edge loop (no unroll).
// Stats contention guard: 8 rotating stats copies (bid&7), summed in
// finalize (per-word atomic contention 1627 -> ~203).
// Pipeline: K1 init | K2 deg_acc | K3 counts | K4 scan(<=2048, pair/thread)
// | K5 fill | K6 tile(+self+y+stats) | K7 finalize | K8 out.
//
// Workspace (floats): deg N | y 20N | stats 8*256 | params 64, then (ints)
// counts NB | bstart NB+1 | cursor NB*32 | erec8 2*E (uint2).

#define F 20
#define NSTAT 230
#define SROWS 128
#define BSZ 256
#define TBSZ 256
#define CPAD 32  // cursor padding stride (ints) = 128B line

__global__ void k_init(float* __restrict__ deg, float* __restrict__ stats, int N) {
  int i = blockIdx.x * blockDim.x + threadIdx.x;
  if (i < N) deg[i] = 0.f;  // self-loop added at use: deg_true = deg + 1
  if (i < 8 * 256) stats[i] = 0.f;
}

// plain degree histogram: atomics spread over 832KB -> no hot lines.
__global__ void k_deg_acc(const int* __restrict__ dst, float* __restrict__ deg, int E) {
  int e = blockIdx.x * blockDim.x + threadIdx.x;
  if (e < E) atomicAdd(&deg[dst[e]], 1.0f);
}

// counts[b] = sum of deg over rows [b*128, b*128+128) — no atomics.
__global__ __launch_bounds__(128) void k_counts(const float* __restrict__ deg,
                                                int* __restrict__ counts, int N) {
  __shared__ float s[128];
  int t = threadIdx.x;
  long row = (long)blockIdx.x * SROWS + t;
  s[t] = (row < N) ? deg[row] : 0.f;
  __syncthreads();
  for (int off = 64; off; off >>= 1) {
    if (t < off) s[t] += s[t + off];
    __syncthreads();
  }
  if (t == 0) counts[blockIdx.x] = (int)(s[0] + 0.5f);
}

// exclusive scan of NB (<=2048) bucket counts, pair-per-thread Hillis-Steele;
// writes bstart + padded cursor.
__global__ __launch_bounds__(1024) void k_scan(const int* __restrict__ counts,
                                               int* __restrict__ bstart,
                                               int* __restrict__ cursor,
                                               int NB, int E) {
  __shared__ int s[1024];
  int t = threadIdx.x;
  int i0 = 2 * t, i1 = 2 * t + 1;
  int c0 = (i0 < NB) ? counts[i0] : 0;
  int c1 = (i1 < NB) ? counts[i1] : 0;
  int sum = c0 + c1;
  s[t] = sum;
  __syncthreads();
  for (int off = 1; off < 1024; off <<= 1) {
    int v = (t >= off) ? s[t - off] : 0;
    __syncthreads();
    s[t] += v;
    __syncthreads();
  }
  int base = s[t] - sum;  // exclusive prefix over pairs
  if (i0 < NB) { bstart[i0] = base;      cursor[i0 * CPAD] = base; }
  if (i1 < NB) { bstart[i1] = base + c0; cursor[i1 * CPAD] = base + c0; }
  if (t == 0) bstart[NB] = E;
}

// bucket fill, payload inline, packed uint2 record (src | dlow<<22, ns bits).
__global__ void k_fill(const int* __restrict__ src, const int* __restrict__ dst,
                       const float* __restrict__ deg, int* __restrict__ cursor,
                       uint2* __restrict__ erec8, int E) {
  int e = blockIdx.x * blockDim.x + threadIdx.x;
  if (e >= E) return;
  int s = src[e];
  int d = dst[e];
  int pos = atomicAdd(&cursor[(d >> 7) * CPAD], 1);
  uint2 r;
  r.x = (unsigned int)s | ((unsigned int)(d & 127) << 22);
  r.y = __float_as_uint(rsqrtf(deg[s] + 1.0f));
  erec8[pos] = r;
}

// Block b owns dst rows [b*128, b*128+128): accumulate bucket edges into an
// LDS tile via LDS atomics, add self-term, write y once, stats from LDS.
__global__ __launch_bounds__(TBSZ) void k_tile(
    const uint2* __restrict__ erec8, const int* __restrict__ bstart,
    const float* __restrict__ deg,
    const float* __restrict__ state, const float* __restrict__ edge_attr,
    float* __restrict__ y, float* __restrict__ stats, int N, int Ns) {
  __shared__ float tile[SROWS * F];  // 10 KB
  int t = threadIdx.x;

  for (int i4 = t; i4 < SROWS * 5; i4 += TBSZ)
    *reinterpret_cast<float4*>(tile + i4 * 4) = make_float4(0.f, 0.f, 0.f, 0.f);
  __syncthreads();

  // ---- edge accumulation: tile[dlow][f] += ns * x[s][f] ----
  int start = bstart[blockIdx.x];
  int cnt = bstart[blockIdx.x + 1] - start;
  int sb = Ns * F;
  int nit = cnt * F;
  for (int it = t; it < nit; it += TBSZ) {
    int le = it / F;
    int f = it - le * F;
    uint2 r = erec8[start + le];  // sequential 8B load
    int s = r.x & 0x3FFFFF;
    int dlow = r.x >> 22;
    float ns = __uint_as_float(r.y);
    int xi = s * F + f;
    float x = (xi < sb) ? state[xi] : edge_attr[xi - sb];  // THE gather
    atomicAdd(&tile[dlow * F + f], ns * x);
  }
  __syncthreads();

  // ---- self-term: y_full = dinv*(z + dinv*x); single streaming writeback ----
  long rowbase = (long)blockIdx.x * SROWS;
  for (int i4 = t; i4 < SROWS * 5; i4 += TBSZ) {
    int rl = i4 / 5;
    int q = i4 - rl * 5;
    long row = rowbase + rl;
    float4 v = make_float4(0.f, 0.f, 0.f, 0.f);
    if (row < N) {
      float4 zv = *reinterpret_cast<const float4*>(tile + i4 * 4);
      const float* xrow = (row < (long)Ns) ? (state + row * F)
                                           : (edge_attr + (row - Ns) * F);
      float4 xv = *reinterpret_cast<const float4*>(xrow + q * 4);
      float di = rsqrtf(deg[row] + 1.0f);
      v.x = di * (zv.x + di * xv.x);
      v.y = di * (zv.y + di * xv.y);
      v.z = di * (zv.z + di * xv.z);
      v.w = di * (zv.w + di * xv.w);
      *reinterpret_cast<float4*>(y + row * F + q * 4) = v;  // for k_out
    }
    *reinterpret_cast<float4*>(tile + i4 * 4) = v;
  }
  __syncthreads();

  // ---- stats from LDS tile (128 rows); 8 rotating copies cut contention ----
  float* st = stats + (blockIdx.x & 7) * 256;
  if (t < F) {
    float a0 = 0.f, a1 = 0.f, a2 = 0.f, a3 = 0.f;
    for (int r = 0; r < SROWS; r += 4) {
      a0 += tile[(r + 0) * F + t];
      a1 += tile[(r + 1) * F + t];
      a2 += tile[(r + 2) * F + t];
      a3 += tile[(r + 3) * F + t];
    }
    atomicAdd(&st[t], (a0 + a1) + (a2 + a3));
  } else if (t < NSTAT) {
    int k = t - F, i = 0;
    while (k >= F - i) { k -= F - i; i++; }
    int ci = i, cj = i + k;
    float a0 = 0.f, a1 = 0.f, a2 = 0.f, a3 = 0.f;
    for (int r = 0; r < SROWS; r += 4) {
      a0 += tile[(r + 0) * F + ci] * tile[(r + 0) * F + cj];
      a1 += tile[(r + 1) * F + ci] * tile[(r + 1) * F + cj];
      a2 += tile[(r + 2) * F + ci] * tile[(r + 2) * F + cj];
      a3 += tile[(r + 3) * F + ci] * tile[(r + 3) * F + cj];
    }
    atomicAdd(&st[t], (a0 + a1) + (a2 + a3));
  }
}

// Single block, 256 threads, launch_bounds(256,1): 4 waves -> up to 512
// VGPR/thread; w[4][20] + m0[20] + m1[20] live in registers (round-4 proven).
// Sums the 8 stats copies on load.
__global__ __launch_bounds__(256, 1) void k_finalize(
    const float* __restrict__ stats,
    const float* __restrict__ W_gcn,
    const float* __restrict__ gamma,
    const float* __restrict__ beta,
    const float* __restrict__ W_lin,
    const float* __restrict__ b_lin,
    float* __restrict__ params,
    int N, int H) {
  __shared__ float Cu_s[210];
  __shared__ float ybar_s[F];
  __shared__ float part[4][44];
  int t = threadIdx.x;
  int lane = t & 63;
  int wv = t >> 6;
  float invN = 1.0f / (float)N;
  if (t < F) {
    float s = 0.f;
    for (int k = 0; k < 8; ++k) s += stats[k * 256 + t];
    ybar_s[t] = s * invN;
  }
  __syncthreads();
  if (t < 210) {
    int k = t, i = 0;
    while (k >= F - i) { k -= F - i; i++; }
    int j = i + k;
    float sv = 0.f;
    for (int c = 0; c < 8; ++c) sv += stats[c * 256 + F + t];
    float cv = sv * invN - ybar_s[i] * ybar_s[j];
    Cu_s[t] = (i == j) ? cv : 2.0f * cv;  // fold symmetry factor
  }
  __syncthreads();

  float m0[F], m1[F];
  #pragma unroll
  for (int f = 0; f < F; ++f) { m0[f] = 0.f; m1[f] = 0.f; }
  float d0 = 0.f, d1 = 0.f;

  for (int hb = 0; hb < H; hb += 4 * 256) {
    float w[4][F];
    float var[4];
    int hh[4];
    bool act[4];
    #pragma unroll
    for (int c = 0; c < 4; ++c) {
      int h = hb + c * 256 + t;
      act[c] = (h < H);
      hh[c] = act[c] ? h : 0;
      var[c] = 0.f;
      #pragma unroll
      for (int f = 0; f < F; ++f) {
        float x = W_gcn[f * H + hh[c]];  // coalesced over t
        w[c][f] = act[c] ? x : 0.f;
      }
    }
    int p = 0;
    #pragma unroll
    for (int i = 0; i < F; ++i) {
      #pragma unroll
      for (int j = i; j < F; ++j) {
        float cu = Cu_s[p];  // uniform broadcast, reused 4x
        ++p;
        #pragma unroll
        for (int c = 0; c < 4; ++c) var[c] += cu * (w[c][i] * w[c][j]);
      }
    }
    #pragma unroll
    for (int c = 0; c < 4; ++c) {
      float sg = act[c] ? (gamma[hh[c]] * rsqrtf(var[c] + 1e-5f)) : 0.f;
      float wl0 = W_lin[hh[c] * 2 + 0], wl1 = W_lin[hh[c] * 2 + 1];
      float s0 = sg * wl0, s1 = sg * wl1;
      #pragma unroll
      for (int f = 0; f < F; ++f) { m0[f] += w[c][f] * s0; m1[f] += w[c][f] * s1; }
      float bt = act[c] ? beta[hh[c]] : 0.f;
      d0 += bt * wl0;
      d1 += bt * wl1;
    }
  }

  #pragma unroll
  for (int f = 0; f < F; ++f) {
    float v0 = m0[f], v1 = m1[f];
    #pragma unroll
    for (int off = 32; off; off >>= 1) {
      v0 += __shfl_xor(v0, off);
      v1 += __shfl_xor(v1, off);
    }
    if (lane == 0) { part[wv][2 * f] = v0; part[wv][2 * f + 1] = v1; }
  }
  #pragma unroll
  for (int off = 32; off; off >>= 1) {
    d0 += __shfl_xor(d0, off);
    d1 += __shfl_xor(d1, off);
  }
  if (lane == 0) { part[wv][40] = d0; part[wv][41] = d1; }
  __syncthreads();

  if (t < 42) {
    float acc = 0.f;
    for (int w2 = 0; w2 < 4; ++w2) acc += part[w2][t];
    if (t >= 40) acc += b_lin[t - 40];
    params[t] = acc;
  } else if (t < 62) {
    params[t] = ybar_s[t - 42];
  }
}

// thread per node: logits = (y[n]-ybar) @ M + d; relu; 2-way softmax.
__global__ void k_out(const float* __restrict__ y,
                      const float* __restrict__ params,
                      float* __restrict__ out, int N) {
  __shared__ float P[64];
  if (threadIdx.x < 62) P[threadIdx.x] = params[threadIdx.x];
  __syncthreads();
  int n = blockIdx.x * blockDim.x + threadIdx.x;
  if (n >= N) return;
  const float4* yr4 = reinterpret_cast<const float4*>(y + (size_t)n * F);
  float l0 = P[40], l1 = P[41];
  #pragma unroll
  for (int k = 0; k < 5; ++k) {
    float4 q = yr4[k];
    float vv[4] = {q.x, q.y, q.z, q.w};
    #pragma unroll
    for (int u = 0; u < 4; ++u) {
      int f = 4 * k + u;
      float dv = vv[u] - P[42 + f];
      l0 += dv * P[2 * f + 0];
      l1 += dv * P[2 * f + 1];
    }
  }
  l0 = fmaxf(l0, 0.f);
  l1 = fmaxf(l1, 0.f);
  float m = fmaxf(l0, l1);
  float e0 = __expf(l0 - m), e1 = __expf(l1 - m);
  float inv = 1.0f / (e0 + e1);
  float2 o2;
  o2.x = e0 * inv;
  o2.y = e1 * inv;
  reinterpret_cast<float2*>(out)[n] = o2;
}

extern "C" void kernel_launch(void* const* d_in, const int* in_sizes, int n_in,
                              void* d_out, int out_size, void* d_ws, size_t ws_size,
                              hipStream_t stream) {
  const float* state     = (const float*)d_in[0];
  const float* edge_attr = (const float*)d_in[1];
  const int*   eidx      = (const int*)d_in[2];
  const float* W_gcn     = (const float*)d_in[3];
  // d_in[4] = b_gcn: cancels inside batchnorm, unused.
  const float* gamma     = (const float*)d_in[5];
  const float* beta      = (const float*)d_in[6];
  const float* W_lin     = (const float*)d_in[7];
  const float* b_lin     = (const float*)d_in[8];
  float* out = (float*)d_out;

  int Ns = in_sizes[0] / F;
  int E  = in_sizes[2] / 2;
  int N  = Ns + in_sizes[1] / F;
  int H  = in_sizes[4];

  const int* src = eidx;
  const int* dst = eidx + E;

  int NB = (N + SROWS - 1) / SROWS;  // 1627 for N=208192 (<=2048 for k_scan)

  float* ws     = (float*)d_ws;
  float* deg    = ws;
  float* y      = ws + N;
  float* stats  = y + (size_t)N * F;      // 8*256 floats
  float* params = stats + 8 * 256;
  int*   counts = (int*)(params + 64);
  int*   bstart = counts + NB;
  int*   cursor = bstart + NB + 1;        // NB*CPAD ints, padded
  uint2* erec8  = (uint2*)(cursor + NB * CPAD);

  k_init<<<(N + BSZ - 1) / BSZ, BSZ, 0, stream>>>(deg, stats, N);
  k_deg_acc<<<(E + BSZ - 1) / BSZ, BSZ, 0, stream>>>(dst, deg, E);
  k_counts<<<NB, 128, 0, stream>>>(deg, counts, N);
  k_scan<<<1, 1024, 0, stream>>>(counts, bstart, cursor, NB, E);
  k_fill<<<(E + BSZ - 1) / BSZ, BSZ, 0, stream>>>(src, dst, deg, cursor,
                                                  erec8, E);
  k_tile<<<NB, TBSZ, 0, stream>>>(erec8, bstart, deg, state, edge_attr,
                                  y, stats, N, Ns);
  k_finalize<<<1, 256, 0, stream>>>(stats, W_gcn, gamma, beta, W_lin, b_lin,
                                    params, N, H);
  k_out<<<(N + BSZ - 1) / BSZ, BSZ, 0, stream>>>(y, params, out, N);
}